// Round 1
// baseline (117.488 us; speedup 1.0000x reference)
//
#include <hip/hip_runtime.h>

typedef unsigned short ushort_t;
typedef __attribute__((ext_vector_type(8))) short bf16x8;
typedef __attribute__((ext_vector_type(8))) unsigned short ushort8;
typedef __attribute__((ext_vector_type(4))) float f32x4;

__device__ __forceinline__ unsigned short f2bf(float f) {
  union { float f; unsigned u; } x; x.f = f;
  unsigned r = x.u + 0x7FFFu + ((x.u >> 16) & 1u);   // round-to-nearest-even
  return (unsigned short)(r >> 16);
}

// ---------------- chain part 1: g[b][q][y][c][z] = sum_r f1[b,q,r,y]*lf[c,r,z]
__global__ void chain_g_kernel(const float* __restrict__ f1,
                               const float* __restrict__ lf,
                               float* __restrict__ g) {
  int idx = blockIdx.x * 256 + threadIdx.x;           // 32768 total
  int z = idx & 7, c = (idx >> 3) & 3, y = (idx >> 5) & 7,
      q = (idx >> 8) & 15, b = idx >> 12;
  float s = 0.f;
  #pragma unroll
  for (int r = 0; r < 16; ++r)
    s += f1[((b * 16 + q) * 16 + r) * 8 + y] * lf[(c * 16 + r) * 8 + z];
  g[idx] = s;
}

// ---------------- chain part 2: chainT[o][k] = sum_q f0[a,p,q,x]*g[b,q,y,c,z]
// o = (x*8+y)*8+z ; k = ((a*8+b)*4+c)*4+p
__global__ void chain_kernel(const float* __restrict__ f0,
                             const float* __restrict__ g,
                             ushort_t* __restrict__ chainT) {
  int idx = blockIdx.x * 256 + threadIdx.x;           // 524288 total = o*1024+k
  int k = idx & 1023, o = idx >> 10;
  int p = k & 3, c = (k >> 2) & 3, b = (k >> 4) & 7, a = k >> 7;
  int z = o & 7, y = (o >> 3) & 7, x = o >> 6;
  float s = 0.f;
  #pragma unroll
  for (int q = 0; q < 16; ++q)
    s += f0[((a * 4 + p) * 16 + q) * 8 + x] *
         g[(((b * 16 + q) * 8 + y) * 4 + c) * 8 + z];
  chainT[idx] = f2bf(s);
}

// ---------------- depthwise 3x3 conv -> t[m][k] bf16 (K-contiguous)
// m = n*1024 + h*32 + w ; k = cin*4 + p
__global__ __launch_bounds__(256) void conv_kernel(const float* __restrict__ in,
                                                   const float* __restrict__ sf,
                                                   ushort_t* __restrict__ t) {
  __shared__ float in_lds[16][3][34];
  __shared__ float sf_l[36];
  int tid = threadIdx.x;
  int n = blockIdx.x >> 5, h = blockIdx.x & 31;
  if (tid < 36) sf_l[tid] = sf[tid];
  int w = tid >> 3, gg = tid & 7;                     // w:0..31  gg:0..7
  for (int c0 = 0; c0 < 256; c0 += 16) {
    __syncthreads();
    #pragma unroll
    for (int i = 0; i < 6; ++i) {                     // 1536 loads / 256 thr
      int e = tid + i * 256;
      int cc = e / 96, rem = e % 96;
      int r = rem >> 5, ww = rem & 31;
      int hh = h - 1 + r;
      float v = 0.f;
      if (hh >= 0 && hh < 32)
        v = in[(((size_t)n * 256 + c0 + cc) * 32 + hh) * 32 + ww];
      in_lds[cc][r][ww + 1] = v;
    }
    if (tid < 48) { in_lds[tid / 3][tid % 3][0] = 0.f; in_lds[tid / 3][tid % 3][33] = 0.f; }
    __syncthreads();
    ushort8 outv;
    #pragma unroll
    for (int s = 0; s < 2; ++s) {
      int cc = gg * 2 + s;
      float a0 = 0.f, a1 = 0.f, a2 = 0.f, a3 = 0.f;
      #pragma unroll
      for (int r = 0; r < 3; ++r)
        #pragma unroll
        for (int dw = 0; dw < 3; ++dw) {
          float xv = in_lds[cc][r][w + dw];
          a0 += xv * sf_l[0 * 9 + r * 3 + dw];
          a1 += xv * sf_l[1 * 9 + r * 3 + dw];
          a2 += xv * sf_l[2 * 9 + r * 3 + dw];
          a3 += xv * sf_l[3 * 9 + r * 3 + dw];
        }
      outv[s * 4 + 0] = f2bf(a0); outv[s * 4 + 1] = f2bf(a1);
      outv[s * 4 + 2] = f2bf(a2); outv[s * 4 + 3] = f2bf(a3);
    }
    size_t m = (size_t)n * 1024 + h * 32 + w;
    *(ushort8*)&t[m * 1024 + (size_t)(c0 + gg * 2) * 4] = outv;  // 16B, coalesced in 128B groups
  }
}

// ---------------- GEMM: out[m][o] = sum_k t[m][k]*chainT[o][k] + bias[o]
// 128x128 tile, BK=64, 4 waves (2x2), 4x4 frags of mfma_f32_16x16x32_bf16
__global__ __launch_bounds__(256) void gemm_kernel(const ushort_t* __restrict__ tA,
                                                   const ushort_t* __restrict__ tB,
                                                   const float* __restrict__ bias,
                                                   float* __restrict__ out) {
  __shared__ __align__(16) ushort_t As[128 * 64];
  __shared__ __align__(16) ushort_t Bs[128 * 64];
  int tid = threadIdx.x;
  int tile_m = (int)(blockIdx.x >> 2) * 128;
  int tile_n = (int)(blockIdx.x & 3) * 128;
  int lane = tid & 63, wave = tid >> 6;
  int wm = (wave >> 1) * 64, wn = (wave & 1) * 64;
  int lr = lane & 15, kg = lane >> 4;
  f32x4 acc[4][4];
  #pragma unroll
  for (int i = 0; i < 4; ++i)
    #pragma unroll
    for (int j = 0; j < 4; ++j) acc[i][j] = (f32x4){0.f, 0.f, 0.f, 0.f};

  int srow = tid >> 3;            // 0..31
  int kc8 = (tid & 7) * 8;        // element offset of this thread's 16B chunk
  const ushort_t* srcA = tA + (size_t)(tile_m + srow) * 1024 + kc8;
  const ushort_t* srcB = tB + (size_t)(tile_n + srow) * 1024 + kc8;

  for (int kt = 0; kt < 16; ++kt) {
    int k0 = kt * 64;
    __syncthreads();
    #pragma unroll
    for (int i = 0; i < 4; ++i) {
      __builtin_amdgcn_global_load_lds(
          (const __attribute__((address_space(1))) void*)(srcA + (size_t)i * 32 * 1024 + k0),
          (__attribute__((address_space(3))) void*)(&As[(i * 32 + srow) * 64 + kc8]),
          16, 0, 0);
      __builtin_amdgcn_global_load_lds(
          (const __attribute__((address_space(1))) void*)(srcB + (size_t)i * 32 * 1024 + k0),
          (__attribute__((address_space(3))) void*)(&Bs[(i * 32 + srow) * 64 + kc8]),
          16, 0, 0);
    }
    __syncthreads();
    #pragma unroll
    for (int kk = 0; kk < 64; kk += 32) {
      bf16x8 af[4], bfv[4];
      #pragma unroll
      for (int i = 0; i < 4; ++i)
        af[i] = *(const bf16x8*)&As[(wm + i * 16 + lr) * 64 + kk + kg * 8];
      #pragma unroll
      for (int j = 0; j < 4; ++j)
        bfv[j] = *(const bf16x8*)&Bs[(wn + j * 16 + lr) * 64 + kk + kg * 8];
      #pragma unroll
      for (int i = 0; i < 4; ++i)
        #pragma unroll
        for (int j = 0; j < 4; ++j)
          acc[i][j] = __builtin_amdgcn_mfma_f32_16x16x32_bf16(af[i], bfv[j], acc[i][j], 0, 0, 0);
    }
  }

  // epilogue: lane holds D[m=kg*4+r][o=lr] per 16x16 frag; 4 consecutive m -> one f32x4 store
  #pragma unroll
  for (int i = 0; i < 4; ++i)
    #pragma unroll
    for (int j = 0; j < 4; ++j) {
      int m = tile_m + wm + i * 16 + kg * 4;
      int o = tile_n + wn + j * 16 + lr;
      float bv = bias[o];
      f32x4 v = acc[i][j];
      v[0] += bv; v[1] += bv; v[2] += bv; v[3] += bv;
      size_t addr = (size_t)(m >> 10) * 524288 + (size_t)o * 1024 + (size_t)(m & 1023);
      *(f32x4*)&out[addr] = v;
    }
}

extern "C" void kernel_launch(void* const* d_in, const int* in_sizes, int n_in,
                              void* d_out, int out_size, void* d_ws, size_t ws_size,
                              hipStream_t stream) {
  (void)in_sizes; (void)n_in; (void)out_size; (void)ws_size;
  const float* in   = (const float*)d_in[0];
  const float* sf   = (const float*)d_in[1];
  const float* f0   = (const float*)d_in[2];
  const float* f1   = (const float*)d_in[3];
  const float* lf   = (const float*)d_in[4];
  const float* bias = (const float*)d_in[5];
  float* out = (float*)d_out;

  char* ws = (char*)d_ws;
  ushort_t* t      = (ushort_t*)ws;                          // 32768*1024*2  = 64 MB
  ushort_t* chainT = (ushort_t*)(ws + 67108864);             // 512*1024*2    = 1 MB
  float*    g      = (float*)(ws + 67108864 + 1048576);      // 32768*4       = 128 KB

  hipLaunchKernelGGL(chain_g_kernel, dim3(128),  dim3(256), 0, stream, f1, lf, g);
  hipLaunchKernelGGL(chain_kernel,   dim3(2048), dim3(256), 0, stream, f0, g, chainT);
  hipLaunchKernelGGL(conv_kernel,    dim3(1024), dim3(256), 0, stream, in, sf, t);
  hipLaunchKernelGGL(gemm_kernel,    dim3(1024), dim3(256), 0, stream, t, chainT, bias, out);
}

// Round 2
// 114.333 us; speedup vs baseline: 1.0276x; 1.0276x over previous
//
#include <hip/hip_runtime.h>

typedef unsigned short ushort_t;
typedef __attribute__((ext_vector_type(8))) short bf16x8;
typedef __attribute__((ext_vector_type(8))) unsigned short ushort8;
typedef __attribute__((ext_vector_type(4))) float f32x4;

__device__ __forceinline__ unsigned short f2bf(float f) {
  union { float f; unsigned u; } x; x.f = f;
  unsigned r = x.u + 0x7FFFu + ((x.u >> 16) & 1u);   // round-to-nearest-even
  return (unsigned short)(r >> 16);
}

// ---------------- chain part 1: g[b][q][y][c][z] = sum_r f1[b,q,r,y]*lf[c,r,z]
__global__ void chain_g_kernel(const float* __restrict__ f1,
                               const float* __restrict__ lf,
                               float* __restrict__ g) {
  int idx = blockIdx.x * 256 + threadIdx.x;           // 32768 total
  int z = idx & 7, c = (idx >> 3) & 3, y = (idx >> 5) & 7,
      q = (idx >> 8) & 15, b = idx >> 12;
  float s = 0.f;
  #pragma unroll
  for (int r = 0; r < 16; ++r)
    s += f1[((b * 16 + q) * 16 + r) * 8 + y] * lf[(c * 16 + r) * 8 + z];
  g[idx] = s;
}

// ---------------- chain part 2: chainT[o][k] = sum_q f0[a,p,q,x]*g[b,q,y,c,z]
// o = (x*8+y)*8+z ; k = ((a*8+b)*4+c)*4+p
__global__ void chain_kernel(const float* __restrict__ f0,
                             const float* __restrict__ g,
                             ushort_t* __restrict__ chainT) {
  int idx = blockIdx.x * 256 + threadIdx.x;           // 524288 total = o*1024+k
  int k = idx & 1023, o = idx >> 10;
  int p = k & 3, c = (k >> 2) & 3, b = (k >> 4) & 7, a = k >> 7;
  int z = o & 7, y = (o >> 3) & 7, x = o >> 6;
  float s = 0.f;
  #pragma unroll
  for (int q = 0; q < 16; ++q)
    s += f0[((a * 4 + p) * 16 + q) * 8 + x] *
         g[(((b * 16 + q) * 8 + y) * 4 + c) * 8 + z];
  chainT[idx] = f2bf(s);
}

// ---------------- depthwise 3x3 conv -> t[m][k] bf16 (K-contiguous)
// block = (n, h-pair, channel-quarter). grid = 32*16*4 = 2048 blocks.
// LDS row layout per (ch,r): width 40 floats; [4..35]=w 0..31, [3]=left zero, [36]=right zero.
__global__ __launch_bounds__(256) void conv_kernel(const float* __restrict__ in,
                                                   const float* __restrict__ sf,
                                                   ushort_t* __restrict__ t) {
  __shared__ float in_lds[64][164];    // 64 ch x (4 rows * 40 + 4 pad) -> ch stride 164 (=4 mod 32)
  __shared__ float sf_l[36];
  int bid = blockIdx.x;
  int cq = bid & 3, h2 = (bid >> 2) & 15, n = bid >> 6;
  int h0 = h2 * 2;                     // output rows h0, h0+1; input rows h0-1 .. h0+2
  int tid = threadIdx.x;
  if (tid < 36) sf_l[tid] = sf[tid];
  // zero halo columns
  { int ch = tid >> 2, r = tid & 3;
    in_lds[ch][r * 40 + 3] = 0.f;
    in_lds[ch][r * 40 + 36] = 0.f; }
  // load 64 ch x 4 rows x 32 w as float4 (2048 float4, 8 per thread)
  const float* inb = in + ((size_t)n * 256 + cq * 64) * 1024;
  #pragma unroll
  for (int i = 0; i < 8; ++i) {
    int e = tid + i * 256;             // 0..2047
    int ch = e >> 5, rem = e & 31;
    int r = rem >> 3, w4 = rem & 7;
    int hh = h0 - 1 + r;
    float4 v = make_float4(0.f, 0.f, 0.f, 0.f);
    if (hh >= 0 && hh < 32)
      v = *(const float4*)&inb[(size_t)ch * 1024 + hh * 32 + w4 * 4];
    *(float4*)&in_lds[ch][r * 40 + 4 + w4 * 4] = v;
  }
  __syncthreads();

  // cache filters in registers
  float sfr[36];
  #pragma unroll
  for (int i = 0; i < 36; ++i) sfr[i] = sf_l[i];

  int w = tid >> 3, gg = tid & 7;      // w:0..31  gg:0..7
  size_t m0 = (size_t)n * 1024 + (size_t)h0 * 32 + w;
  #pragma unroll
  for (int j = 0; j < 4; ++j) {
    float acc[2][2][4];                // [hh][b][p]
    #pragma unroll
    for (int b = 0; b < 2; ++b) {
      int ch = j * 16 + gg * 2 + b;
      float vals[4][3];
      #pragma unroll
      for (int r = 0; r < 4; ++r)
        #pragma unroll
        for (int dw = 0; dw < 3; ++dw)
          vals[r][dw] = in_lds[ch][r * 40 + 3 + w + dw];
      #pragma unroll
      for (int hh = 0; hh < 2; ++hh)
        #pragma unroll
        for (int p = 0; p < 4; ++p) {
          float s = 0.f;
          #pragma unroll
          for (int dr = 0; dr < 3; ++dr)
            #pragma unroll
            for (int dw = 0; dw < 3; ++dw)
              s += vals[hh + dr][dw] * sfr[p * 9 + dr * 3 + dw];
          acc[hh][b][p] = s;
        }
    }
    #pragma unroll
    for (int hh = 0; hh < 2; ++hh) {
      ushort8 outv;
      #pragma unroll
      for (int b = 0; b < 2; ++b)
        #pragma unroll
        for (int p = 0; p < 4; ++p) outv[b * 4 + p] = f2bf(acc[hh][b][p]);
      // k = (cq*64 + j*16 + gg*2)*4 : lanes gg contiguous -> 128B segments
      *(ushort8*)&t[(m0 + hh * 32) * 1024 + (size_t)(cq * 256 + j * 64 + gg * 8)] = outv;
    }
  }
}

// ---------------- GEMM: out[m][o] = sum_k t[m][k]*chainT[o][k] + bias[o]
// 128x128 tile, BK=64, 4 waves (2x2), double-buffered LDS, 1 barrier / K-step
__global__ __launch_bounds__(256) void gemm_kernel(const ushort_t* __restrict__ tA,
                                                   const ushort_t* __restrict__ tB,
                                                   const float* __restrict__ bias,
                                                   float* __restrict__ out) {
  __shared__ __align__(16) ushort_t As[2][128 * 64];
  __shared__ __align__(16) ushort_t Bs[2][128 * 64];
  int tid = threadIdx.x;
  int tile_m = (int)(blockIdx.x >> 2) * 128;
  int tile_n = (int)(blockIdx.x & 3) * 128;
  int lane = tid & 63, wave = tid >> 6;
  int wm = (wave >> 1) * 64, wn = (wave & 1) * 64;
  int lr = lane & 15, kg = lane >> 4;
  f32x4 acc[4][4];
  #pragma unroll
  for (int i = 0; i < 4; ++i)
    #pragma unroll
    for (int j = 0; j < 4; ++j) acc[i][j] = (f32x4){0.f, 0.f, 0.f, 0.f};

  int srow = tid >> 3;            // 0..31
  int kc8 = (tid & 7) * 8;        // element offset of this thread's 16B chunk
  const ushort_t* srcA = tA + (size_t)(tile_m + srow) * 1024 + kc8;
  const ushort_t* srcB = tB + (size_t)(tile_n + srow) * 1024 + kc8;

#define STAGE(buf, k0)                                                                       \
  _Pragma("unroll")                                                                          \
  for (int i = 0; i < 4; ++i) {                                                              \
    __builtin_amdgcn_global_load_lds(                                                        \
        (const __attribute__((address_space(1))) void*)(srcA + (size_t)i * 32 * 1024 + (k0)),\
        (__attribute__((address_space(3))) void*)(&As[buf][(i * 32 + srow) * 64 + kc8]),     \
        16, 0, 0);                                                                           \
    __builtin_amdgcn_global_load_lds(                                                        \
        (const __attribute__((address_space(1))) void*)(srcB + (size_t)i * 32 * 1024 + (k0)),\
        (__attribute__((address_space(3))) void*)(&Bs[buf][(i * 32 + srow) * 64 + kc8]),     \
        16, 0, 0);                                                                           \
  }

  STAGE(0, 0)
  __syncthreads();

  for (int kt = 0; kt < 16; ++kt) {
    int cur = kt & 1;
    if (kt < 15) { STAGE(cur ^ 1, (kt + 1) * 64) }
    #pragma unroll
    for (int kk = 0; kk < 64; kk += 32) {
      bf16x8 af[4], bfv[4];
      #pragma unroll
      for (int i = 0; i < 4; ++i)
        af[i] = *(const bf16x8*)&As[cur][(wm + i * 16 + lr) * 64 + kk + kg * 8];
      #pragma unroll
      for (int j = 0; j < 4; ++j)
        bfv[j] = *(const bf16x8*)&Bs[cur][(wn + j * 16 + lr) * 64 + kk + kg * 8];
      #pragma unroll
      for (int i = 0; i < 4; ++i)
        #pragma unroll
        for (int j = 0; j < 4; ++j)
          acc[i][j] = __builtin_amdgcn_mfma_f32_16x16x32_bf16(af[i], bfv[j], acc[i][j], 0, 0, 0);
    }
    __syncthreads();   // drains vmcnt (stage for next buf) + protects cur for overwrite
  }
#undef STAGE

  // epilogue: lane holds D[m=kg*4+r][o=lr] per 16x16 frag; 4 consecutive m -> one f32x4 store
  #pragma unroll
  for (int i = 0; i < 4; ++i)
    #pragma unroll
    for (int j = 0; j < 4; ++j) {
      int m = tile_m + wm + i * 16 + kg * 4;
      int o = tile_n + wn + j * 16 + lr;
      float bv = bias[o];
      f32x4 v = acc[i][j];
      v[0] += bv; v[1] += bv; v[2] += bv; v[3] += bv;
      size_t addr = (size_t)(m >> 10) * 524288 + (size_t)o * 1024 + (size_t)(m & 1023);
      *(f32x4*)&out[addr] = v;
    }
}

extern "C" void kernel_launch(void* const* d_in, const int* in_sizes, int n_in,
                              void* d_out, int out_size, void* d_ws, size_t ws_size,
                              hipStream_t stream) {
  (void)in_sizes; (void)n_in; (void)out_size; (void)ws_size;
  const float* in   = (const float*)d_in[0];
  const float* sf   = (const float*)d_in[1];
  const float* f0   = (const float*)d_in[2];
  const float* f1   = (const float*)d_in[3];
  const float* lf   = (const float*)d_in[4];
  const float* bias = (const float*)d_in[5];
  float* out = (float*)d_out;

  char* ws = (char*)d_ws;
  ushort_t* t      = (ushort_t*)ws;                          // 32768*1024*2  = 64 MB
  ushort_t* chainT = (ushort_t*)(ws + 67108864);             // 512*1024*2    = 1 MB
  float*    g      = (float*)(ws + 67108864 + 1048576);      // 32768*4       = 128 KB

  hipLaunchKernelGGL(chain_g_kernel, dim3(128),  dim3(256), 0, stream, f1, lf, g);
  hipLaunchKernelGGL(chain_kernel,   dim3(2048), dim3(256), 0, stream, f0, g, chainT);
  hipLaunchKernelGGL(conv_kernel,    dim3(2048), dim3(256), 0, stream, in, sf, t);
  hipLaunchKernelGGL(gemm_kernel,    dim3(1024), dim3(256), 0, stream, t, chainT, bias, out);
}

// Round 3
// 77.899 us; speedup vs baseline: 1.5082x; 1.4677x over previous
//
#include <hip/hip_runtime.h>

typedef unsigned short ushort_t;
typedef __attribute__((ext_vector_type(8))) short bf16x8;
typedef __attribute__((ext_vector_type(8))) unsigned short ushort8;
typedef __attribute__((ext_vector_type(4))) float f32x4;

__device__ __forceinline__ unsigned short f2bf(float f) {
  union { float f; unsigned u; } x; x.f = f;
  unsigned r = x.u + 0x7FFFu + ((x.u >> 16) & 1u);   // round-to-nearest-even
  return (unsigned short)(r >> 16);
}

// ---------------- chain part 1: g[b][q][y][c][z] = sum_r f1[b,q,r,y]*lf[c,r,z]
__global__ void chain_g_kernel(const float* __restrict__ f1,
                               const float* __restrict__ lf,
                               float* __restrict__ g) {
  int idx = blockIdx.x * 256 + threadIdx.x;           // 32768 total
  int z = idx & 7, c = (idx >> 3) & 3, y = (idx >> 5) & 7,
      q = (idx >> 8) & 15, b = idx >> 12;
  float s = 0.f;
  #pragma unroll
  for (int r = 0; r < 16; ++r)
    s += f1[((b * 16 + q) * 16 + r) * 8 + y] * lf[(c * 16 + r) * 8 + z];
  g[idx] = s;
}

// ---------------- chain part 2: chainT[o][k] = sum_q f0[a,p,q,x]*g[b,q,y,c,z]
// o = (x*8+y)*8+z ; k = ((a*8+b)*4+c)*4+p
__global__ void chain_kernel(const float* __restrict__ f0,
                             const float* __restrict__ g,
                             ushort_t* __restrict__ chainT) {
  int idx = blockIdx.x * 256 + threadIdx.x;           // 524288 total = o*1024+k
  int k = idx & 1023, o = idx >> 10;
  int p = k & 3, c = (k >> 2) & 3, b = (k >> 4) & 7, a = k >> 7;
  int z = o & 7, y = (o >> 3) & 7, x = o >> 6;
  float s = 0.f;
  #pragma unroll
  for (int q = 0; q < 16; ++q)
    s += f0[((a * 4 + p) * 16 + q) * 8 + x] *
         g[(((b * 16 + q) * 8 + y) * 4 + c) * 8 + z];
  chainT[idx] = f2bf(s);
}

// ---------------- depthwise 3x3 conv -> t[m][k] bf16 (K-contiguous)
__global__ __launch_bounds__(256) void conv_kernel(const float* __restrict__ in,
                                                   const float* __restrict__ sf,
                                                   ushort_t* __restrict__ t) {
  __shared__ float in_lds[64][164];
  __shared__ float sf_l[36];
  int bid = blockIdx.x;
  int cq = bid & 3, h2 = (bid >> 2) & 15, n = bid >> 6;
  int h0 = h2 * 2;
  int tid = threadIdx.x;
  if (tid < 36) sf_l[tid] = sf[tid];
  { int ch = tid >> 2, r = tid & 3;
    in_lds[ch][r * 40 + 3] = 0.f;
    in_lds[ch][r * 40 + 36] = 0.f; }
  const float* inb = in + ((size_t)n * 256 + cq * 64) * 1024;
  #pragma unroll
  for (int i = 0; i < 8; ++i) {
    int e = tid + i * 256;
    int ch = e >> 5, rem = e & 31;
    int r = rem >> 3, w4 = rem & 7;
    int hh = h0 - 1 + r;
    float4 v = make_float4(0.f, 0.f, 0.f, 0.f);
    if (hh >= 0 && hh < 32)
      v = *(const float4*)&inb[(size_t)ch * 1024 + hh * 32 + w4 * 4];
    *(float4*)&in_lds[ch][r * 40 + 4 + w4 * 4] = v;
  }
  __syncthreads();
  float sfr[36];
  #pragma unroll
  for (int i = 0; i < 36; ++i) sfr[i] = sf_l[i];
  int w = tid >> 3, gg = tid & 7;
  size_t m0 = (size_t)n * 1024 + (size_t)h0 * 32 + w;
  #pragma unroll
  for (int j = 0; j < 4; ++j) {
    float acc[2][2][4];
    #pragma unroll
    for (int b = 0; b < 2; ++b) {
      int ch = j * 16 + gg * 2 + b;
      float vals[4][3];
      #pragma unroll
      for (int r = 0; r < 4; ++r)
        #pragma unroll
        for (int dw = 0; dw < 3; ++dw)
          vals[r][dw] = in_lds[ch][r * 40 + 3 + w + dw];
      #pragma unroll
      for (int hh = 0; hh < 2; ++hh)
        #pragma unroll
        for (int p = 0; p < 4; ++p) {
          float s = 0.f;
          #pragma unroll
          for (int dr = 0; dr < 3; ++dr)
            #pragma unroll
            for (int dw = 0; dw < 3; ++dw)
              s += vals[hh + dr][dw] * sfr[p * 9 + dr * 3 + dw];
          acc[hh][b][p] = s;
        }
    }
    #pragma unroll
    for (int hh = 0; hh < 2; ++hh) {
      ushort8 outv;
      #pragma unroll
      for (int b = 0; b < 2; ++b)
        #pragma unroll
        for (int p = 0; p < 4; ++p) outv[b * 4 + p] = f2bf(acc[hh][b][p]);
      *(ushort8*)&t[(m0 + hh * 32) * 1024 + (size_t)(cq * 256 + j * 64 + gg * 8)] = outv;
    }
  }
}

// ---------------- GEMM: out[m][o] = sum_k t[m][k]*chainT[o][k] + bias[o]
// 256x256 tile, BK=64, 8 waves (2Mx4N), 8-phase schedule, counted vmcnt,
// XOR-swizzled LDS (col ^= (row&7)*8 elems), raw s_barrier, setprio.
#define AS1 __attribute__((address_space(1)))
#define AS3 __attribute__((address_space(3)))
#define BARRIER __builtin_amdgcn_s_barrier()
#define SBAR    __builtin_amdgcn_sched_barrier(0)
#define VMCNT4  asm volatile("s_waitcnt vmcnt(4)" ::: "memory")
#define VMCNT0  asm volatile("s_waitcnt vmcnt(0)" ::: "memory")

__global__ __launch_bounds__(512, 2) void gemm_kernel(const ushort_t* __restrict__ tA,
                                                      const ushort_t* __restrict__ tB,
                                                      const float* __restrict__ bias,
                                                      float* __restrict__ out) {
  __shared__ __align__(16) ushort_t smem[65536];   // 128 KB: As[2][16384] | Bs[2][16384]
  int tid = threadIdx.x;
  int bid = blockIdx.x;                            // 256 blocks
  int wg = (bid & 7) * 32 + (bid >> 3);            // bijective XCD swizzle (256%8==0)
  int tile_m = (wg >> 1) * 256;
  int tile_n = (wg & 1) * 256;

  int lane = tid & 63, wv = tid >> 6;
  int wm2 = wv >> 2, wn4 = wv & 3;
  int lr = lane & 15, kg = lane >> 4;
  // swizzled k-offsets (elements) for ks=0/1: (ks*32 + kg*8) ^ (lane&7)*8
  int kph0 = ((kg * 8) ^ ((lane & 7) * 8));
  int kph1 = ((32 + kg * 8) ^ ((lane & 7) * 8));
  int arow = wm2 * 128 + lr;
  int brow = wn4 * 64 + lr;

  // stage addressing: thread tid covers LDS chunk tid (linear); source col pre-swizzled
  int srow = tid >> 3;
  int scol = ((tid & 7) ^ (srow & 7)) * 8;
  const ushort_t* sA = tA + (size_t)(tile_m + srow) * 1024 + scol;
  const ushort_t* sB = tB + (size_t)(tile_n + srow) * 1024 + scol;

#define STAGE_A(buf, koff, h)                                                                  \
  __builtin_amdgcn_global_load_lds((const AS1 void*)(sA + (size_t)((h)*128) * 1024 + (koff)),  \
      (AS3 void*)&smem[(buf)*16384 + (h)*8192 + tid*8], 16, 0, 0);                             \
  __builtin_amdgcn_global_load_lds((const AS1 void*)(sA + (size_t)((h)*128+64) * 1024 + (koff)),\
      (AS3 void*)&smem[(buf)*16384 + (h)*8192 + 4096 + tid*8], 16, 0, 0);
#define STAGE_B(buf, koff, h)                                                                  \
  __builtin_amdgcn_global_load_lds((const AS1 void*)(sB + (size_t)((h)*128) * 1024 + (koff)),  \
      (AS3 void*)&smem[32768 + (buf)*16384 + (h)*8192 + tid*8], 16, 0, 0);                     \
  __builtin_amdgcn_global_load_lds((const AS1 void*)(sB + (size_t)((h)*128+64) * 1024 + (koff)),\
      (AS3 void*)&smem[32768 + (buf)*16384 + (h)*8192 + 4096 + tid*8], 16, 0, 0);

#define READ_A(dst, mbase, buf)                                                                \
  _Pragma("unroll")                                                                            \
  for (int mf = 0; mf < 4; ++mf) {                                                             \
    dst[mf][0] = *(const bf16x8*)&smem[(buf)*16384 + (arow + (mbase) + mf*16)*64 + kph0];      \
    dst[mf][1] = *(const bf16x8*)&smem[(buf)*16384 + (arow + (mbase) + mf*16)*64 + kph1];      \
  }
#define READ_B(dst, nbase, buf)                                                                \
  _Pragma("unroll")                                                                            \
  for (int nf = 0; nf < 2; ++nf) {                                                             \
    dst[nf][0] = *(const bf16x8*)&smem[32768 + (buf)*16384 + (brow + (nbase) + nf*16)*64 + kph0];\
    dst[nf][1] = *(const bf16x8*)&smem[32768 + (buf)*16384 + (brow + (nbase) + nf*16)*64 + kph1];\
  }
#define Q_MFMA(AF, BF, MB, NB)                                                                 \
  __builtin_amdgcn_s_setprio(1);                                                              \
  _Pragma("unroll")                                                                            \
  for (int mf = 0; mf < 4; ++mf)                                                               \
    _Pragma("unroll")                                                                          \
    for (int nf = 0; nf < 2; ++nf)                                                             \
      _Pragma("unroll")                                                                        \
      for (int ks = 0; ks < 2; ++ks)                                                           \
        acc[(MB) + mf][(NB) + nf] = __builtin_amdgcn_mfma_f32_16x16x32_bf16(                   \
            AF[mf][ks], BF[nf][ks], acc[(MB) + mf][(NB) + nf], 0, 0, 0);                       \
  __builtin_amdgcn_s_setprio(0);

  f32x4 acc[8][4];
  #pragma unroll
  for (int i = 0; i < 8; ++i)
    #pragma unroll
    for (int j = 0; j < 4; ++j) acc[i][j] = (f32x4){0.f, 0.f, 0.f, 0.f};

  bf16x8 a1[4][2], a2[4][2], b1[2][2], b2[2][2];

  // prologue: kt0 (buf0) fully + kt1 A halves (buf1); then drain once for startup skew
  STAGE_A(0, 0, 0) STAGE_A(0, 0, 1) STAGE_B(0, 0, 0) STAGE_B(0, 0, 1)
  STAGE_A(1, 64, 0) STAGE_A(1, 64, 1)
  VMCNT0; BARRIER;

#define ITER(I_, FULL)                                                                         \
  {                                                                                            \
    int k1 = (2*(I_)+1)*64, k2 = (2*(I_)+2)*64, k3 = (2*(I_)+3)*64;                            \
    /* p0: q0 of kt even (buf0) */                                                             \
    VMCNT4; SBAR;                                                                              \
    READ_A(a1, 0, 0) READ_B(b1, 0, 0)                                                          \
    STAGE_B(1, k1, 0) SBAR; BARRIER; SBAR;                                                     \
    Q_MFMA(a1, b1, 0, 0) SBAR; BARRIER;                                                        \
    /* p1 */                                                                                   \
    READ_B(b2, 32, 0) STAGE_B(1, k1, 1) SBAR; BARRIER; SBAR;                                   \
    Q_MFMA(a1, b2, 0, 2) SBAR; BARRIER;                                                        \
    /* p2 */                                                                                   \
    READ_A(a2, 64, 0) if (FULL) { STAGE_A(0, k2, 0) } SBAR; BARRIER; SBAR;                     \
    Q_MFMA(a2, b2, 4, 2) SBAR; BARRIER;                                                        \
    /* p3 */                                                                                   \
    if (FULL) { STAGE_A(0, k2, 1) } SBAR; BARRIER; SBAR;                                       \
    Q_MFMA(a2, b1, 4, 0) SBAR; BARRIER;                                                        \
    /* p4: q0 of kt odd (buf1) */                                                              \
    if (FULL) { VMCNT4; } else { VMCNT0; } SBAR;                                               \
    READ_A(a1, 0, 1) READ_B(b1, 0, 1)                                                          \
    if (FULL) { STAGE_B(0, k2, 0) } SBAR; BARRIER; SBAR;                                       \
    Q_MFMA(a1, b1, 0, 0) SBAR; BARRIER;                                                        \
    /* p5 */                                                                                   \
    READ_B(b2, 32, 1) if (FULL) { STAGE_B(0, k2, 1) } SBAR; BARRIER; SBAR;                     \
    Q_MFMA(a1, b2, 0, 2) SBAR; BARRIER;                                                        \
    /* p6 */                                                                                   \
    READ_A(a2, 64, 1) if (FULL) { STAGE_A(1, k3, 0) } SBAR; BARRIER; SBAR;                     \
    Q_MFMA(a2, b2, 4, 2) SBAR; BARRIER;                                                        \
    /* p7 */                                                                                   \
    if (FULL) { STAGE_A(1, k3, 1) } SBAR; BARRIER; SBAR;                                       \
    Q_MFMA(a2, b1, 4, 0) SBAR; BARRIER;                                                        \
  }

  for (int I = 0; I < 7; ++I) ITER(I, 1)
  ITER(7, 0)
#undef ITER

  // epilogue
  #pragma unroll
  for (int mf = 0; mf < 8; ++mf)
    #pragma unroll
    for (int nf = 0; nf < 4; ++nf) {
      int m = tile_m + wm2 * 128 + mf * 16 + kg * 4;
      int o = tile_n + wn4 * 64 + nf * 16 + lr;
      float bv = bias[o];
      f32x4 v = acc[mf][nf];
      v[0] += bv; v[1] += bv; v[2] += bv; v[3] += bv;
      *(f32x4*)&out[(size_t)(m >> 10) * 524288 + (size_t)o * 1024 + (size_t)(m & 1023)] = v;
    }
}

extern "C" void kernel_launch(void* const* d_in, const int* in_sizes, int n_in,
                              void* d_out, int out_size, void* d_ws, size_t ws_size,
                              hipStream_t stream) {
  (void)in_sizes; (void)n_in; (void)out_size; (void)ws_size;
  const float* in   = (const float*)d_in[0];
  const float* sf   = (const float*)d_in[1];
  const float* f0   = (const float*)d_in[2];
  const float* f1   = (const float*)d_in[3];
  const float* lf   = (const float*)d_in[4];
  const float* bias = (const float*)d_in[5];
  float* out = (float*)d_out;

  char* ws = (char*)d_ws;
  ushort_t* t      = (ushort_t*)ws;                          // 64 MB
  ushort_t* chainT = (ushort_t*)(ws + 67108864);             // 1 MB
  float*    g      = (float*)(ws + 67108864 + 1048576);      // 128 KB

  hipLaunchKernelGGL(chain_g_kernel, dim3(128),  dim3(256), 0, stream, f1, lf, g);
  hipLaunchKernelGGL(chain_kernel,   dim3(2048), dim3(256), 0, stream, f0, g, chainT);
  hipLaunchKernelGGL(conv_kernel,    dim3(2048), dim3(256), 0, stream, in, sf, t);
  hipLaunchKernelGGL(gemm_kernel,    dim3(256),  dim3(512), 0, stream, t, chainT, bias, out);
}

// Round 4
// 75.387 us; speedup vs baseline: 1.5585x; 1.0333x over previous
//
#include <hip/hip_runtime.h>

typedef unsigned short ushort_t;
typedef __attribute__((ext_vector_type(8))) short bf16x8;
typedef __attribute__((ext_vector_type(8))) unsigned short ushort8;
typedef __attribute__((ext_vector_type(4))) float f32x4;

__device__ __forceinline__ unsigned short f2bf(float f) {
  union { float f; unsigned u; } x; x.f = f;
  unsigned r = x.u + 0x7FFFu + ((x.u >> 16) & 1u);   // round-to-nearest-even
  return (unsigned short)(r >> 16);
}

// ---------------- chain part 1: g[b][q][y][c][z] = sum_r f1[b,q,r,y]*lf[c,r,z]
__global__ void chain_g_kernel(const float* __restrict__ f1,
                               const float* __restrict__ lf,
                               float* __restrict__ g) {
  int idx = blockIdx.x * 256 + threadIdx.x;           // 32768 total
  int z = idx & 7, c = (idx >> 3) & 3, y = (idx >> 5) & 7,
      q = (idx >> 8) & 15, b = idx >> 12;
  float s = 0.f;
  #pragma unroll
  for (int r = 0; r < 16; ++r)
    s += f1[((b * 16 + q) * 16 + r) * 8 + y] * lf[(c * 16 + r) * 8 + z];
  g[idx] = s;
}

// ---------------- chain part 2: chainT[o][k] = sum_q f0[a,p,q,x]*g[b,q,y,c,z]
// o = (x*8+y)*8+z ; k = ((a*8+b)*4+c)*4+p
__global__ void chain_kernel(const float* __restrict__ f0,
                             const float* __restrict__ g,
                             ushort_t* __restrict__ chainT) {
  int idx = blockIdx.x * 256 + threadIdx.x;           // 524288 total = o*1024+k
  int k = idx & 1023, o = idx >> 10;
  int p = k & 3, c = (k >> 2) & 3, b = (k >> 4) & 7, a = k >> 7;
  int z = o & 7, y = (o >> 3) & 7, x = o >> 6;
  float s = 0.f;
  #pragma unroll
  for (int q = 0; q < 16; ++q)
    s += f0[((a * 4 + p) * 16 + q) * 8 + x] *
         g[(((b * 16 + q) * 8 + y) * 4 + c) * 8 + z];
  chainT[idx] = f2bf(s);
}

// ---------------- depthwise 3x3 conv -> t[m][k] bf16 (K-contiguous)
// block = (n, h-quad, channel-quarter). grid = 32*8*4 = 1024 blocks.
// 4 output rows/block -> halo amplification 6/4 = 1.5x (was 2x).
__global__ __launch_bounds__(256) void conv_kernel(const float* __restrict__ in,
                                                   const float* __restrict__ sf,
                                                   ushort_t* __restrict__ t) {
  __shared__ float in_lds[64][244];    // 64 ch x (6 rows * 40 + 4 pad); 62.5 KB -> 2 blocks/CU
  __shared__ float sf_l[36];
  int bid = blockIdx.x;
  int cq = bid & 3, h4 = (bid >> 2) & 7, n = bid >> 5;
  int h0 = h4 * 4;                     // output rows h0..h0+3; input rows h0-1..h0+4
  int tid = threadIdx.x;
  if (tid < 36) sf_l[tid] = sf[tid];
  // zero halo columns: 64 ch x 6 rows
  for (int e = tid; e < 384; e += 256) {
    int ch = e / 6, r = e % 6;
    in_lds[ch][r * 40 + 3] = 0.f;
    in_lds[ch][r * 40 + 36] = 0.f;
  }
  // load 64 ch x 6 rows x 32 w as float4 (3072 float4, 12 per thread)
  const float* inb = in + ((size_t)n * 256 + cq * 64) * 1024;
  #pragma unroll
  for (int i = 0; i < 12; ++i) {
    int e = tid + i * 256;             // 0..3071
    int ch = e / 48, rem = e % 48;
    int r = rem >> 3, w4 = rem & 7;
    int hh = h0 - 1 + r;
    float4 v = make_float4(0.f, 0.f, 0.f, 0.f);
    if (hh >= 0 && hh < 32)
      v = *(const float4*)&inb[(size_t)ch * 1024 + hh * 32 + w4 * 4];
    *(float4*)&in_lds[ch][r * 40 + 4 + w4 * 4] = v;
  }
  __syncthreads();
  float sfr[36];
  #pragma unroll
  for (int i = 0; i < 36; ++i) sfr[i] = sf_l[i];
  int w = tid >> 3, gg = tid & 7;      // w:0..31  gg:0..7
  size_t m0 = (size_t)n * 1024 + (size_t)h0 * 32 + w;
  #pragma unroll
  for (int j = 0; j < 4; ++j) {
    float acc[4][2][4];                // [hh][b][p]
    #pragma unroll
    for (int b = 0; b < 2; ++b) {
      int ch = j * 16 + gg * 2 + b;
      float vals[6][3];
      #pragma unroll
      for (int r = 0; r < 6; ++r)
        #pragma unroll
        for (int dw = 0; dw < 3; ++dw)
          vals[r][dw] = in_lds[ch][r * 40 + 3 + w + dw];
      #pragma unroll
      for (int hh = 0; hh < 4; ++hh)
        #pragma unroll
        for (int p = 0; p < 4; ++p) {
          float s = 0.f;
          #pragma unroll
          for (int dr = 0; dr < 3; ++dr)
            #pragma unroll
            for (int dw = 0; dw < 3; ++dw)
              s += vals[hh + dr][dw] * sfr[p * 9 + dr * 3 + dw];
          acc[hh][b][p] = s;
        }
    }
    #pragma unroll
    for (int hh = 0; hh < 4; ++hh) {
      ushort8 outv;
      #pragma unroll
      for (int b = 0; b < 2; ++b)
        #pragma unroll
        for (int p = 0; p < 4; ++p) outv[b * 4 + p] = f2bf(acc[hh][b][p]);
      *(ushort8*)&t[(m0 + hh * 32) * 1024 + (size_t)(cq * 256 + j * 64 + gg * 8)] = outv;
    }
  }
}

// ---------------- GEMM: out[m][o] = sum_k t[m][k]*chainT[o][k] + bias[o]
// 256x256 tile, BK=64, 8 waves (2Mx4N), 8-phase schedule, counted vmcnt,
// XOR-swizzled LDS, raw s_barrier, setprio. NO sched_barrier (m141: pinning regresses).
#define AS1 __attribute__((address_space(1)))
#define AS3 __attribute__((address_space(3)))
#define BARRIER __builtin_amdgcn_s_barrier()
#define VMCNT4  asm volatile("s_waitcnt vmcnt(4)" ::: "memory")
#define VMCNT0  asm volatile("s_waitcnt vmcnt(0)" ::: "memory")

__global__ __launch_bounds__(512, 2) void gemm_kernel(const ushort_t* __restrict__ tA,
                                                      const ushort_t* __restrict__ tB,
                                                      const float* __restrict__ bias,
                                                      float* __restrict__ out) {
  __shared__ __align__(16) ushort_t smem[65536];   // 128 KB: As[2][16384] | Bs[2][16384]
  int tid = threadIdx.x;
  int bid = blockIdx.x;                            // 256 blocks
  int wg = (bid & 7) * 32 + (bid >> 3);            // bijective XCD swizzle (256%8==0)
  int tile_m = (wg >> 1) * 256;
  int tile_n = (wg & 1) * 256;

  int lane = tid & 63, wv = tid >> 6;
  int wm2 = wv >> 2, wn4 = wv & 3;
  int lr = lane & 15, kg = lane >> 4;
  int kph0 = ((kg * 8) ^ ((lane & 7) * 8));
  int kph1 = ((32 + kg * 8) ^ ((lane & 7) * 8));
  int arow = wm2 * 128 + lr;
  int brow = wn4 * 64 + lr;

  int srow = tid >> 3;
  int scol = ((tid & 7) ^ (srow & 7)) * 8;
  const ushort_t* sA = tA + (size_t)(tile_m + srow) * 1024 + scol;
  const ushort_t* sB = tB + (size_t)(tile_n + srow) * 1024 + scol;

#define STAGE_A(buf, koff, h)                                                                  \
  __builtin_amdgcn_global_load_lds((const AS1 void*)(sA + (size_t)((h)*128) * 1024 + (koff)),  \
      (AS3 void*)&smem[(buf)*16384 + (h)*8192 + tid*8], 16, 0, 0);                             \
  __builtin_amdgcn_global_load_lds((const AS1 void*)(sA + (size_t)((h)*128+64) * 1024 + (koff)),\
      (AS3 void*)&smem[(buf)*16384 + (h)*8192 + 4096 + tid*8], 16, 0, 0);
#define STAGE_B(buf, koff, h)                                                                  \
  __builtin_amdgcn_global_load_lds((const AS1 void*)(sB + (size_t)((h)*128) * 1024 + (koff)),  \
      (AS3 void*)&smem[32768 + (buf)*16384 + (h)*8192 + tid*8], 16, 0, 0);                     \
  __builtin_amdgcn_global_load_lds((const AS1 void*)(sB + (size_t)((h)*128+64) * 1024 + (koff)),\
      (AS3 void*)&smem[32768 + (buf)*16384 + (h)*8192 + 4096 + tid*8], 16, 0, 0);

#define READ_A(dst, mbase, buf)                                                                \
  _Pragma("unroll")                                                                            \
  for (int mf = 0; mf < 4; ++mf) {                                                             \
    dst[mf][0] = *(const bf16x8*)&smem[(buf)*16384 + (arow + (mbase) + mf*16)*64 + kph0];      \
    dst[mf][1] = *(const bf16x8*)&smem[(buf)*16384 + (arow + (mbase) + mf*16)*64 + kph1];      \
  }
#define READ_B(dst, nbase, buf)                                                                \
  _Pragma("unroll")                                                                            \
  for (int nf = 0; nf < 2; ++nf) {                                                             \
    dst[nf][0] = *(const bf16x8*)&smem[32768 + (buf)*16384 + (brow + (nbase) + nf*16)*64 + kph0];\
    dst[nf][1] = *(const bf16x8*)&smem[32768 + (buf)*16384 + (brow + (nbase) + nf*16)*64 + kph1];\
  }
#define Q_MFMA(AF, BF, MB, NB)                                                                 \
  __builtin_amdgcn_s_setprio(1);                                                              \
  _Pragma("unroll")                                                                            \
  for (int mf = 0; mf < 4; ++mf)                                                               \
    _Pragma("unroll")                                                                          \
    for (int nf = 0; nf < 2; ++nf)                                                             \
      _Pragma("unroll")                                                                        \
      for (int ks = 0; ks < 2; ++ks)                                                           \
        acc[(MB) + mf][(NB) + nf] = __builtin_amdgcn_mfma_f32_16x16x32_bf16(                   \
            AF[mf][ks], BF[nf][ks], acc[(MB) + mf][(NB) + nf], 0, 0, 0);                       \
  __builtin_amdgcn_s_setprio(0);

  f32x4 acc[8][4];
  #pragma unroll
  for (int i = 0; i < 8; ++i)
    #pragma unroll
    for (int j = 0; j < 4; ++j) acc[i][j] = (f32x4){0.f, 0.f, 0.f, 0.f};

  bf16x8 a1[4][2], a2[4][2], b1[2][2], b2[2][2];

  // prologue: kt0 (buf0) fully + kt1 A halves (buf1); drain only buf0 (vmcnt(4)),
  // barrier makes buf0 globally visible; A-buf1 stays in flight.
  STAGE_A(0, 0, 0) STAGE_A(0, 0, 1) STAGE_B(0, 0, 0) STAGE_B(0, 0, 1)
  STAGE_A(1, 64, 0) STAGE_A(1, 64, 1)
  VMCNT4; BARRIER;

#define ITER(I_, FULL)                                                                         \
  {                                                                                            \
    int k1 = (2*(I_)+1)*64, k2 = (2*(I_)+2)*64, k3 = (2*(I_)+3)*64;                            \
    /* p0: q0 of kt even (buf0) */                                                             \
    VMCNT4;                                                                                    \
    READ_A(a1, 0, 0) READ_B(b1, 0, 0)                                                          \
    STAGE_B(1, k1, 0) BARRIER;                                                                 \
    Q_MFMA(a1, b1, 0, 0) BARRIER;                                                              \
    /* p1 */                                                                                   \
    READ_B(b2, 32, 0) STAGE_B(1, k1, 1) BARRIER;                                               \
    Q_MFMA(a1, b2, 0, 2) BARRIER;                                                              \
    /* p2 */                                                                                   \
    READ_A(a2, 64, 0) if (FULL) { STAGE_A(0, k2, 0) } BARRIER;                                 \
    Q_MFMA(a2, b2, 4, 2) BARRIER;                                                              \
    /* p3 */                                                                                   \
    if (FULL) { STAGE_A(0, k2, 1) } BARRIER;                                                   \
    Q_MFMA(a2, b1, 4, 0) BARRIER;                                                              \
    /* p4: q0 of kt odd (buf1) */                                                              \
    if (FULL) { VMCNT4; } else { VMCNT0; }                                                     \
    READ_A(a1, 0, 1) READ_B(b1, 0, 1)                                                          \
    if (FULL) { STAGE_B(0, k2, 0) } BARRIER;                                                   \
    Q_MFMA(a1, b1, 0, 0) BARRIER;                                                              \
    /* p5 */                                                                                   \
    READ_B(b2, 32, 1) if (FULL) { STAGE_B(0, k2, 1) } BARRIER;                                 \
    Q_MFMA(a1, b2, 0, 2) BARRIER;                                                              \
    /* p6 */                                                                                   \
    READ_A(a2, 64, 1) if (FULL) { STAGE_A(1, k3, 0) } BARRIER;                                 \
    Q_MFMA(a2, b2, 4, 2) BARRIER;                                                              \
    /* p7 */                                                                                   \
    if (FULL) { STAGE_A(1, k3, 1) } BARRIER;                                                   \
    Q_MFMA(a2, b1, 4, 0) BARRIER;                                                              \
  }

  for (int I = 0; I < 7; ++I) ITER(I, 1)
  ITER(7, 0)
#undef ITER

  // epilogue
  #pragma unroll
  for (int mf = 0; mf < 8; ++mf)
    #pragma unroll
    for (int nf = 0; nf < 4; ++nf) {
      int m = tile_m + wm2 * 128 + mf * 16 + kg * 4;
      int o = tile_n + wn4 * 64 + nf * 16 + lr;
      float bv = bias[o];
      f32x4 v = acc[mf][nf];
      v[0] += bv; v[1] += bv; v[2] += bv; v[3] += bv;
      *(f32x4*)&out[(size_t)(m >> 10) * 524288 + (size_t)o * 1024 + (size_t)(m & 1023)] = v;
    }
}

extern "C" void kernel_launch(void* const* d_in, const int* in_sizes, int n_in,
                              void* d_out, int out_size, void* d_ws, size_t ws_size,
                              hipStream_t stream) {
  (void)in_sizes; (void)n_in; (void)out_size; (void)ws_size;
  const float* in   = (const float*)d_in[0];
  const float* sf   = (const float*)d_in[1];
  const float* f0   = (const float*)d_in[2];
  const float* f1   = (const float*)d_in[3];
  const float* lf   = (const float*)d_in[4];
  const float* bias = (const float*)d_in[5];
  float* out = (float*)d_out;

  char* ws = (char*)d_ws;
  ushort_t* t      = (ushort_t*)ws;                          // 64 MB
  ushort_t* chainT = (ushort_t*)(ws + 67108864);             // 1 MB
  float*    g      = (float*)(ws + 67108864 + 1048576);      // 128 KB

  hipLaunchKernelGGL(chain_g_kernel, dim3(128),  dim3(256), 0, stream, f1, lf, g);
  hipLaunchKernelGGL(chain_kernel,   dim3(2048), dim3(256), 0, stream, f0, g, chainT);
  hipLaunchKernelGGL(conv_kernel,    dim3(1024), dim3(256), 0, stream, in, sf, t);
  hipLaunchKernelGGL(gemm_kernel,    dim3(256),  dim3(512), 0, stream, t, chainT, bias, out);
}